// Round 2
// baseline (125.830 us; speedup 1.0000x reference)
//
#include <hip/hip_runtime.h>

#define N 4096
#define D 512
#define C 64
#define MARGIN 1.0f
#define TILE 128
#define NTILES (N / TILE)                 // 32
#define NTRI (NTILES * (NTILES + 1) / 2)  // 528 triangular blocks
#define FINF 3.0e38f
#define SLOTW 16
#define PCAP 1024      // per-block LDS pair-record capacity (mean 244, +48 sigma)
#define LOSSB 128      // loss_kernel blocks

typedef __attribute__((ext_vector_type(8))) short short8;
typedef __attribute__((ext_vector_type(4))) float floatx4;

__device__ __forceinline__ unsigned short f2bf(float f) {
  unsigned int u = __float_as_uint(f);
  u += 0x7FFFu + ((u >> 16) & 1u);  // RNE
  return (unsigned short)(u >> 16);
}

// K1: fp32 -> bf16 + exact fp32 squared norms. Blocks 0..N-1: one row each.
// Blocks 0..15 also init an_sq to +inf. Block N: zero accs/done/pair_cursor.
__global__ __launch_bounds__(256) void prep_kernel(const float* __restrict__ E,
                                                   unsigned short* __restrict__ Ebf,
                                                   float* __restrict__ norms,
                                                   unsigned int* __restrict__ an_sq_bits,
                                                   unsigned int* __restrict__ accs_u,
                                                   unsigned int* __restrict__ ctrl) {
  const int row = blockIdx.x;
  const int tid = threadIdx.x;
  if (row == N) {  // control-init block
    for (int k = tid; k < C * SLOTW; k += 256) accs_u[k] = 0u;
    if (tid < 2) ctrl[tid] = 0u;  // ctrl[0]=pair_cursor, ctrl[1]=done
    return;
  }
  if (row < 16) an_sq_bits[row * 256 + tid] = 0x7F800000u;  // +inf
  const float2 v = reinterpret_cast<const float2*>(E + (size_t)row * D)[tid];
  float s = v.x * v.x + v.y * v.y;
  unsigned int packed = ((unsigned int)f2bf(v.y) << 16) | (unsigned int)f2bf(v.x);
  reinterpret_cast<unsigned int*>(Ebf + (size_t)row * D)[tid] = packed;
  for (int off = 32; off > 0; off >>= 1) s += __shfl_down(s, off);
  __shared__ float wsum[4];
  if ((tid & 63) == 0) wsum[tid >> 6] = s;
  __syncthreads();
  if (tid == 0) norms[row] = wsum[0] + wsum[1] + wsum[2] + wsum[3];
}

// K2: E*E^T via bf16 MFMA, REGISTER-DIRECT operand loads (no LDS staging, no
// K-loop barriers). Ebf (4 MB) is L2/L3-resident (FETCH_SIZE showed 17 MB vs
// 135 MB logical), so LDS staging was pure overhead: DMA + 2 barriers per chunk
// with a vmcnt(0) drain each. Fragment layout of mfma_16x16x32_bf16 lets each
// lane fetch its 8 contiguous bf16 (16 B) straight from the row — one
// global_load_dwordx4 with immediate offset per fragment. The compiler is free
// to hoist loads across MFMAs (counted vmcnt, AITER-style) with no barriers.
// Fused epilogue unchanged: (a) masked min over negatives -> atomicMin;
// (b) emit same-class pairs (i<j) as records, LDS-compacted, one cursor-add.
__global__ __launch_bounds__(256, 2) void gemm_min_kernel(const unsigned short* __restrict__ Ebf,
                                                          const float* __restrict__ norms,
                                                          const int* __restrict__ targets,
                                                          unsigned int* __restrict__ an_sq_bits,
                                                          uint2* __restrict__ pairs,
                                                          unsigned int* __restrict__ ctrl) {
  const int u = blockIdx.x;
  int i = (int)((sqrtf(8.0f * (float)u + 1.0f) - 1.0f) * 0.5f);
  while ((i + 1) * (i + 2) / 2 <= u) ++i;
  while (i * (i + 1) / 2 > u) --i;
  const int tm = u - i * (i + 1) / 2;
  const int tn = i;

  __shared__ float s_rmin[2][TILE];
  __shared__ float s_cmin[2][TILE];
  __shared__ unsigned int s_pkey[PCAP];  // 4 KB
  __shared__ float s_psq[PCAP];          // 4 KB
  __shared__ unsigned int s_pcnt, s_pbase;

  const int tid = threadIdx.x;
  const int wave = tid >> 6, lane = tid & 63;
  const int quad = lane >> 4, l16 = lane & 15;
  const int wr = wave >> 1, wc = wave & 1;  // wave owns rows [wr*64,+64) x cols [wc*64,+64)
  const int rowBase = tm * TILE, colBase = tn * TILE;
  if (tid == 0) s_pcnt = 0u;

  // Per-fragment global base pointers. Fragment s of A: row rowBase+wr*64+s*16+l16,
  // k-bytes (ks*4+quad)*16 within each 128 B chunk -> base + quad*16, imm offs
  // c*128 + ks*64 (max 960 B, fits 13-bit signed immediate).
  const unsigned char* pA[4];
  const unsigned char* pB[4];
#pragma unroll
  for (int s = 0; s < 4; s++) {
    pA[s] = (const unsigned char*)Ebf +
            (size_t)(rowBase + wr * 64 + s * 16 + l16) * (D * 2) + quad * 16;
    pB[s] = (const unsigned char*)Ebf +
            (size_t)(colBase + wc * 64 + s * 16 + l16) * (D * 2) + quad * 16;
  }

  floatx4 acc[4][4];
#pragma unroll
  for (int a = 0; a < 4; a++)
#pragma unroll
    for (int b = 0; b < 4; b++) acc[a][b] = (floatx4){0.f, 0.f, 0.f, 0.f};

  // 16 half-chunk steps (8 chunks x 2), fully unrolled; no barriers anywhere.
#pragma unroll
  for (int c = 0; c < 8; ++c) {
#pragma unroll
    for (int ks = 0; ks < 2; ks++) {
      const int off = c * 128 + ks * 64;
      short8 af[4], bf[4];
#pragma unroll
      for (int s = 0; s < 4; s++) {
        af[s] = *reinterpret_cast<const short8*>(pA[s] + off);
        bf[s] = *reinterpret_cast<const short8*>(pB[s] + off);
      }
#pragma unroll
      for (int sm = 0; sm < 4; sm++)
#pragma unroll
        for (int sn = 0; sn < 4; sn++)
          acc[sm][sn] = __builtin_amdgcn_mfma_f32_16x16x32_bf16(af[sm], bf[sn], acc[sm][sn], 0, 0, 0);
    }
  }

  // Epilogue. C/D layout: col = lane&15, row = quad*4 + reg (m89/m91).
  int tcol[4], gcolv[4];
  float ncol[4];
#pragma unroll
  for (int sn = 0; sn < 4; sn++) {
    const int gc = colBase + wc * 64 + sn * 16 + l16;
    gcolv[sn] = gc;
    tcol[sn] = targets[gc];
    ncol[sn] = norms[gc];
  }
  float colmin[4] = {FINF, FINF, FINF, FINF};
#pragma unroll
  for (int sm = 0; sm < 4; sm++) {
#pragma unroll
    for (int r = 0; r < 4; r++) {
      const int rloc = wr * 64 + sm * 16 + quad * 4 + r;
      const int grow = rowBase + rloc;
      const int trow = targets[grow];
      const float nrow = norms[grow];
      float rowmin = FINF;
#pragma unroll
      for (int sn = 0; sn < 4; sn++) {
        const float sq = fmaxf(nrow + ncol[sn] - 2.0f * acc[sm][sn][r], 0.0f);
        if (tcol[sn] != trow) {
          rowmin = fminf(rowmin, sq);
          colmin[sn] = fminf(colmin[sn], sq);
        } else if (grow < gcolv[sn]) {  // same-class anchor-positive pair (i<j): emit
          const unsigned int idx = atomicAdd(&s_pcnt, 1u);
          if (idx < PCAP) {
            s_pkey[idx] = ((unsigned int)grow << 12) | (unsigned int)gcolv[sn];
            s_psq[idx] = sq;
          } else {  // overflow fallback (astronomically rare): direct global emit
            const unsigned int g = atomicAdd(&ctrl[0], 1u);
            pairs[g] = make_uint2(((unsigned int)grow << 12) | (unsigned int)gcolv[sn],
                                  __float_as_uint(sq));
          }
        }
      }
#pragma unroll
      for (int off = 1; off < 16; off <<= 1) rowmin = fminf(rowmin, __shfl_xor(rowmin, off));
      if (l16 == 0) s_rmin[wc][rloc] = rowmin;
    }
  }
#pragma unroll
  for (int sn = 0; sn < 4; sn++) {
    float cm = colmin[sn];
    cm = fminf(cm, __shfl_xor(cm, 16));
    cm = fminf(cm, __shfl_xor(cm, 32));
    if (quad == 0) s_cmin[wr][wc * 64 + sn * 16 + l16] = cm;
  }
  __syncthreads();
  if (tid < TILE) {
    const float m = fminf(s_rmin[0][tid], s_rmin[1][tid]);
    if (m < FINF) atomicMin(&an_sq_bits[rowBase + tid], __float_as_uint(m));
  } else {
    const int c = tid - TILE;
    const float m = fminf(s_cmin[0][c], s_cmin[1][c]);
    if (m < FINF) atomicMin(&an_sq_bits[colBase + c], __float_as_uint(m));
  }
  // flush the compacted pair list: ONE global cursor-add per block, coalesced copy
  const unsigned int npair = min(s_pcnt, (unsigned int)PCAP);
  if (tid == 0) s_pbase = atomicAdd(&ctrl[0], npair);
  __syncthreads();
  for (unsigned int r = tid; r < npair; r += 256)
    pairs[s_pbase + r] = make_uint2(s_pkey[r], __float_as_uint(s_psq[r]));
}

// K3: flat pass over emitted pair records. loss = relu(sq - an + margin) if the
// mined (euclidean) loss is strictly positive; anchor = smaller index (emit order).
__global__ __launch_bounds__(256) void loss_kernel(const uint2* __restrict__ pairs,
                                                   const unsigned int* __restrict__ an_sq_bits,
                                                   float* __restrict__ accs,
                                                   unsigned int* __restrict__ ctrl,
                                                   float* __restrict__ out) {
  const int tid = threadIdx.x, wave = tid >> 6, lane = tid & 63;
  const unsigned int M = ctrl[0];
  __shared__ float s_sum[4];
  __shared__ unsigned int s_cnt[4], s_cor[4];
  __shared__ int s_last;
  float bsum = 0.f;
  unsigned int bcnt = 0, bcor = 0;
  for (unsigned int r = blockIdx.x * 256 + tid; r < M; r += LOSSB * 256) {
    const uint2 rec = pairs[r];
    const int a = (int)(rec.x >> 12);  // anchor (smaller original index)
    const float sq = __uint_as_float(rec.y);
    const float an = __uint_as_float(an_sq_bits[a]);
    if (sqrtf(sq) - sqrtf(an) + MARGIN > 0.0f) {
      bcnt++;
      bsum += fmaxf(sq - an + MARGIN, 0.0f);
      if (sq < an) bcor++;
    }
  }
#pragma unroll
  for (int off = 32; off > 0; off >>= 1) {
    bsum += __shfl_down(bsum, off);
    bcnt += __shfl_down(bcnt, off);
    bcor += __shfl_down(bcor, off);
  }
  if (lane == 0) { s_sum[wave] = bsum; s_cnt[wave] = bcnt; s_cor[wave] = bcor; }
  __syncthreads();
  if (tid == 0) {
    float* slot = accs + (size_t)(blockIdx.x & (C - 1)) * SLOTW;
    atomicAdd(&slot[0], s_sum[0] + s_sum[1] + s_sum[2] + s_sum[3]);
    atomicAdd((unsigned int*)&slot[1], s_cnt[0] + s_cnt[1] + s_cnt[2] + s_cnt[3]);
    atomicAdd((unsigned int*)&slot[2], s_cor[0] + s_cor[1] + s_cor[2] + s_cor[3]);
    __threadfence();  // release
    s_last = (atomicAdd(&ctrl[1], 1u) == (unsigned int)LOSSB - 1u);
  }
  __syncthreads();
  if (s_last) {  // last block: reduce the 64 slots, finalize the two scalars
    __threadfence();  // acquire
    if (tid < C) {
      float sum = __uint_as_float(atomicAdd((unsigned int*)&accs[(size_t)tid * SLOTW + 0], 0u));
      unsigned int cnt = atomicAdd((unsigned int*)&accs[(size_t)tid * SLOTW + 1], 0u);
      unsigned int cor = atomicAdd((unsigned int*)&accs[(size_t)tid * SLOTW + 2], 0u);
#pragma unroll
      for (int off = 32; off > 0; off >>= 1) {
        sum += __shfl_down(sum, off);
        cnt += __shfl_down(cnt, off);
        cor += __shfl_down(cor, off);
      }
      if (tid == 0) {
        const float denom = (float)(cnt > 0u ? cnt : 1u);
        out[0] = sum / denom;
        out[1] = (float)cor / denom;
      }
    }
  }
}

extern "C" void kernel_launch(void* const* d_in, const int* in_sizes, int n_in,
                              void* d_out, int out_size, void* d_ws, size_t ws_size,
                              hipStream_t stream) {
  const float* E = (const float*)d_in[0];
  const int* targets = (const int*)d_in[1];
  float* out = (float*)d_out;
  char* ws = (char*)d_ws;
  size_t off = 0;
  unsigned short* Ebf = (unsigned short*)(ws + off); off += (size_t)N * D * 2;  // 4 MB
  float* norms = (float*)(ws + off); off += (size_t)N * 4;                      // 16 KB
  unsigned int* an_sq = (unsigned int*)(ws + off); off += (size_t)N * 4;        // 16 KB
  float* accs = (float*)(ws + off); off += (size_t)C * SLOTW * 4;               // 4 KB
  unsigned int* ctrl = (unsigned int*)(ws + off); off += 256;                   // cursor+done
  uint2* pairs = (uint2*)(ws + off);                                            // ~70 MB max

  prep_kernel<<<dim3(N + 1), dim3(256), 0, stream>>>(E, Ebf, norms, an_sq, (unsigned int*)accs, ctrl);
  gemm_min_kernel<<<dim3(NTRI), dim3(256), 0, stream>>>(Ebf, norms, targets, an_sq, pairs, ctrl);
  loss_kernel<<<dim3(LOSSB), dim3(256), 0, stream>>>(pairs, an_sq, accs, ctrl, out);
}

// Round 3
// 110.078 us; speedup vs baseline: 1.1431x; 1.1431x over previous
//
#include <hip/hip_runtime.h>

#define N 4096
#define D 512
#define C 64
#define MARGIN 1.0f
#define TILE 64
#define ROWB 128       // LDS row bytes per chunk (BK=64 bf16); xor-swizzle, no pad
#define NTILES (N / TILE)                 // 64
#define NTRI (NTILES * (NTILES + 1) / 2)  // 2080 triangular blocks (2080 % 8 == 0)
#define FINF 3.0e38f
#define SLOTW 16
#define PCAP 512       // per-block LDS pair-record capacity (mean ~64 at TILE=64)
#define LOSSB 128      // loss_kernel blocks

typedef __attribute__((ext_vector_type(8))) short short8;
typedef __attribute__((ext_vector_type(4))) float floatx4;

__device__ __forceinline__ unsigned short f2bf(float f) {
  unsigned int u = __float_as_uint(f);
  u += 0x7FFFu + ((u >> 16) & 1u);  // RNE
  return (unsigned short)(u >> 16);
}

// async global->LDS DMA, 16 B/lane; LDS dest = wave-uniform base + lane*16 (m97/m104)
__device__ __forceinline__ void gload_lds16(const void* g, void* l) {
  __builtin_amdgcn_global_load_lds(
      (const __attribute__((address_space(1))) unsigned int*)g,
      (__attribute__((address_space(3))) unsigned int*)l, 16, 0, 0);
}

// K1: fp32 -> bf16 + exact fp32 squared norms. Blocks 0..N-1: one row each.
// Blocks 0..15 also init an_sq to +inf. Block N: zero accs/done/pair_cursor.
__global__ __launch_bounds__(256) void prep_kernel(const float* __restrict__ E,
                                                   unsigned short* __restrict__ Ebf,
                                                   float* __restrict__ norms,
                                                   unsigned int* __restrict__ an_sq_bits,
                                                   unsigned int* __restrict__ accs_u,
                                                   unsigned int* __restrict__ ctrl) {
  const int row = blockIdx.x;
  const int tid = threadIdx.x;
  if (row == N) {  // control-init block
    for (int k = tid; k < C * SLOTW; k += 256) accs_u[k] = 0u;
    if (tid < 2) ctrl[tid] = 0u;  // ctrl[0]=pair_cursor, ctrl[1]=done
    return;
  }
  if (row < 16) an_sq_bits[row * 256 + tid] = 0x7F800000u;  // +inf
  const float2 v = reinterpret_cast<const float2*>(E + (size_t)row * D)[tid];
  float s = v.x * v.x + v.y * v.y;
  unsigned int packed = ((unsigned int)f2bf(v.y) << 16) | (unsigned int)f2bf(v.x);
  reinterpret_cast<unsigned int*>(Ebf + (size_t)row * D)[tid] = packed;
  for (int off = 32; off > 0; off >>= 1) s += __shfl_down(s, off);
  __shared__ float wsum[4];
  if ((tid & 63) == 0) wsum[tid >> 6] = s;
  __syncthreads();
  if (tid == 0) norms[row] = wsum[0] + wsum[1] + wsum[2] + wsum[3];
}

// K2: E*E^T via bf16 MFMA, 64x64 tiles (2080 triangular blocks -> ~8 blocks/CU,
// vs 528 at 128-tile: the grid WAS the occupancy cap, rounds 0-2 all sat at
// 13-20% occupancy / 5% MfmaUtil, latency-bound). Single-buffered coalesced
// global_load_lds staging (round-0 verified structure), 2 barriers/chunk.
// XCD-aware bijective swizzle: consecutive triangular u's share the B panel and
// sweep A panels that fit one XCD's 4MB L2. Fused epilogue: (a) masked min over
// negatives -> atomicMin(an_sq_bits); (b) emit same-class pairs (i<j) as
// records {i<<12|j, sq}. LDS-compacted, one cursor-add per block.
__global__ __launch_bounds__(256, 4) void gemm_min_kernel(const unsigned short* __restrict__ Ebf,
                                                          const float* __restrict__ norms,
                                                          const int* __restrict__ targets,
                                                          unsigned int* __restrict__ an_sq_bits,
                                                          uint2* __restrict__ pairs,
                                                          unsigned int* __restrict__ ctrl) {
  // XCD swizzle (m157; bijective since NTRI % 8 == 0): XCD x gets contiguous
  // work range [x*260, (x+1)*260).
  const int u = (blockIdx.x & 7) * (NTRI / 8) + (blockIdx.x >> 3);
  int i = (int)((sqrtf(8.0f * (float)u + 1.0f) - 1.0f) * 0.5f);
  while ((i + 1) * (i + 2) / 2 <= u) ++i;
  while (i * (i + 1) / 2 > u) --i;
  const int tm = u - i * (i + 1) / 2;
  const int tn = i;

  __shared__ alignas(16) unsigned char As[TILE * ROWB];  // 8 KB
  __shared__ alignas(16) unsigned char Bs[TILE * ROWB];  // 8 KB
  __shared__ float s_rmin[2][TILE];
  __shared__ float s_cmin[2][TILE];
  __shared__ unsigned int s_pkey[PCAP];  // 2 KB
  __shared__ float s_psq[PCAP];          // 2 KB
  __shared__ unsigned int s_pcnt, s_pbase;

  const int tid = threadIdx.x;
  const int wave = tid >> 6, lane = tid & 63;
  const int quad = lane >> 4, l16 = lane & 15;
  const int wr = wave >> 1, wc = wave & 1;  // wave owns rows [wr*32,+32) x cols [wc*32,+32)
  const int rowBase = tm * TILE, colBase = tn * TILE;
  if (tid == 0) s_pcnt = 0u;

  // staging: lane covers row lr of an 8-row group, fetches logical chunk (lane&7)^lr
  const int lr = lane >> 3;
  const int lq = (lane & 7) ^ lr;
  const int lofs = lr * (D * 2) + lq * 16;
  const unsigned char* gA = (const unsigned char*)Ebf + (size_t)rowBase * (D * 2);
  const unsigned char* gB = (const unsigned char*)Ebf + (size_t)colBase * (D * 2);

  const int swz = l16 & 7;
  int rA[2], rB[2], cq[2];
#pragma unroll
  for (int s = 0; s < 2; s++) {
    rA[s] = (wr * 32 + s * 16 + l16) * ROWB;
    rB[s] = (wc * 32 + s * 16 + l16) * ROWB;
  }
#pragma unroll
  for (int ks = 0; ks < 2; ks++) cq[ks] = ((ks * 4 + quad) ^ swz) * 16;

  floatx4 acc[2][2];
#pragma unroll
  for (int a = 0; a < 2; a++)
#pragma unroll
    for (int b = 0; b < 2; b++) acc[a][b] = (floatx4){0.f, 0.f, 0.f, 0.f};

  for (int k0b = 0; k0b < D * 2; k0b += 128) {  // 8 chunks of 64 k-elems
#pragma unroll
    for (int t = 0; t < 2; t++) {
      const int g = wave * 2 + t;  // 8 8-row groups per tile, 2 per wave
      gload_lds16(gA + (size_t)g * 8 * (D * 2) + lofs + k0b, As + g * 1024);
      gload_lds16(gB + (size_t)g * 8 * (D * 2) + lofs + k0b, Bs + g * 1024);
    }
    __syncthreads();  // drains DMA (vmcnt) before reads
#pragma unroll
    for (int ks = 0; ks < 2; ks++) {
      short8 af[2], bf[2];
#pragma unroll
      for (int s = 0; s < 2; s++) {
        af[s] = *reinterpret_cast<const short8*>(As + rA[s] + cq[ks]);
        bf[s] = *reinterpret_cast<const short8*>(Bs + rB[s] + cq[ks]);
      }
#pragma unroll
      for (int sm = 0; sm < 2; sm++)
#pragma unroll
        for (int sn = 0; sn < 2; sn++)
          acc[sm][sn] = __builtin_amdgcn_mfma_f32_16x16x32_bf16(af[sm], bf[sn], acc[sm][sn], 0, 0, 0);
    }
    __syncthreads();  // reads done before next chunk's DMA overwrites
  }

  // Epilogue. C/D layout: col = lane&15, row = quad*4 + reg (m89/m91).
  int tcol[2], gcolv[2];
  float ncol[2];
#pragma unroll
  for (int sn = 0; sn < 2; sn++) {
    const int gc = colBase + wc * 32 + sn * 16 + l16;
    gcolv[sn] = gc;
    tcol[sn] = targets[gc];
    ncol[sn] = norms[gc];
  }
  float colmin[2] = {FINF, FINF};
#pragma unroll
  for (int sm = 0; sm < 2; sm++) {
#pragma unroll
    for (int r = 0; r < 4; r++) {
      const int rloc = wr * 32 + sm * 16 + quad * 4 + r;
      const int grow = rowBase + rloc;
      const int trow = targets[grow];
      const float nrow = norms[grow];
      float rowmin = FINF;
#pragma unroll
      for (int sn = 0; sn < 2; sn++) {
        const float sq = fmaxf(nrow + ncol[sn] - 2.0f * acc[sm][sn][r], 0.0f);
        if (tcol[sn] != trow) {
          rowmin = fminf(rowmin, sq);
          colmin[sn] = fminf(colmin[sn], sq);
        } else if (grow < gcolv[sn]) {  // same-class anchor-positive pair (i<j): emit
          const unsigned int idx = atomicAdd(&s_pcnt, 1u);
          if (idx < PCAP) {
            s_pkey[idx] = ((unsigned int)grow << 12) | (unsigned int)gcolv[sn];
            s_psq[idx] = sq;
          } else {  // overflow fallback (astronomically rare): direct global emit
            const unsigned int g = atomicAdd(&ctrl[0], 1u);
            pairs[g] = make_uint2(((unsigned int)grow << 12) | (unsigned int)gcolv[sn],
                                  __float_as_uint(sq));
          }
        }
      }
#pragma unroll
      for (int off = 1; off < 16; off <<= 1) rowmin = fminf(rowmin, __shfl_xor(rowmin, off));
      if (l16 == 0) s_rmin[wc][rloc] = rowmin;
    }
  }
#pragma unroll
  for (int sn = 0; sn < 2; sn++) {
    float cm = colmin[sn];
    cm = fminf(cm, __shfl_xor(cm, 16));
    cm = fminf(cm, __shfl_xor(cm, 32));
    if (quad == 0) s_cmin[wr][wc * 32 + sn * 16 + l16] = cm;
  }
  __syncthreads();
  if (tid < TILE) {
    const float m = fminf(s_rmin[0][tid], s_rmin[1][tid]);
    if (m < FINF) atomicMin(&an_sq_bits[rowBase + tid], __float_as_uint(m));
  } else if (tid < 2 * TILE) {
    const int c = tid - TILE;
    const float m = fminf(s_cmin[0][c], s_cmin[1][c]);
    if (m < FINF) atomicMin(&an_sq_bits[colBase + c], __float_as_uint(m));
  }
  // flush the compacted pair list: ONE global cursor-add per block, coalesced copy
  const unsigned int npair = min(s_pcnt, (unsigned int)PCAP);
  if (tid == 0) s_pbase = atomicAdd(&ctrl[0], npair);
  __syncthreads();
  for (unsigned int r = tid; r < npair; r += 256)
    pairs[s_pbase + r] = make_uint2(s_pkey[r], __float_as_uint(s_psq[r]));
}

// K3: flat pass over emitted pair records. loss = relu(sq - an + margin) if the
// mined (euclidean) loss is strictly positive; anchor = smaller index (emit order).
__global__ __launch_bounds__(256) void loss_kernel(const uint2* __restrict__ pairs,
                                                   const unsigned int* __restrict__ an_sq_bits,
                                                   float* __restrict__ accs,
                                                   unsigned int* __restrict__ ctrl,
                                                   float* __restrict__ out) {
  const int tid = threadIdx.x, wave = tid >> 6, lane = tid & 63;
  const unsigned int M = ctrl[0];
  __shared__ float s_sum[4];
  __shared__ unsigned int s_cnt[4], s_cor[4];
  __shared__ int s_last;
  float bsum = 0.f;
  unsigned int bcnt = 0, bcor = 0;
  for (unsigned int r = blockIdx.x * 256 + tid; r < M; r += LOSSB * 256) {
    const uint2 rec = pairs[r];
    const int a = (int)(rec.x >> 12);  // anchor (smaller original index)
    const float sq = __uint_as_float(rec.y);
    const float an = __uint_as_float(an_sq_bits[a]);
    if (sqrtf(sq) - sqrtf(an) + MARGIN > 0.0f) {
      bcnt++;
      bsum += fmaxf(sq - an + MARGIN, 0.0f);
      if (sq < an) bcor++;
    }
  }
#pragma unroll
  for (int off = 32; off > 0; off >>= 1) {
    bsum += __shfl_down(bsum, off);
    bcnt += __shfl_down(bcnt, off);
    bcor += __shfl_down(bcor, off);
  }
  if (lane == 0) { s_sum[wave] = bsum; s_cnt[wave] = bcnt; s_cor[wave] = bcor; }
  __syncthreads();
  if (tid == 0) {
    float* slot = accs + (size_t)(blockIdx.x & (C - 1)) * SLOTW;
    atomicAdd(&slot[0], s_sum[0] + s_sum[1] + s_sum[2] + s_sum[3]);
    atomicAdd((unsigned int*)&slot[1], s_cnt[0] + s_cnt[1] + s_cnt[2] + s_cnt[3]);
    atomicAdd((unsigned int*)&slot[2], s_cor[0] + s_cor[1] + s_cor[2] + s_cor[3]);
    __threadfence();  // release
    s_last = (atomicAdd(&ctrl[1], 1u) == (unsigned int)LOSSB - 1u);
  }
  __syncthreads();
  if (s_last) {  // last block: reduce the 64 slots, finalize the two scalars
    __threadfence();  // acquire
    if (tid < C) {
      float sum = __uint_as_float(atomicAdd((unsigned int*)&accs[(size_t)tid * SLOTW + 0], 0u));
      unsigned int cnt = atomicAdd((unsigned int*)&accs[(size_t)tid * SLOTW + 1], 0u);
      unsigned int cor = atomicAdd((unsigned int*)&accs[(size_t)tid * SLOTW + 2], 0u);
#pragma unroll
      for (int off = 32; off > 0; off >>= 1) {
        sum += __shfl_down(sum, off);
        cnt += __shfl_down(cnt, off);
        cor += __shfl_down(cor, off);
      }
      if (tid == 0) {
        const float denom = (float)(cnt > 0u ? cnt : 1u);
        out[0] = sum / denom;
        out[1] = (float)cor / denom;
      }
    }
  }
}

extern "C" void kernel_launch(void* const* d_in, const int* in_sizes, int n_in,
                              void* d_out, int out_size, void* d_ws, size_t ws_size,
                              hipStream_t stream) {
  const float* E = (const float*)d_in[0];
  const int* targets = (const int*)d_in[1];
  float* out = (float*)d_out;
  char* ws = (char*)d_ws;
  size_t off = 0;
  unsigned short* Ebf = (unsigned short*)(ws + off); off += (size_t)N * D * 2;  // 4 MB
  float* norms = (float*)(ws + off); off += (size_t)N * 4;                      // 16 KB
  unsigned int* an_sq = (unsigned int*)(ws + off); off += (size_t)N * 4;        // 16 KB
  float* accs = (float*)(ws + off); off += (size_t)C * SLOTW * 4;               // 4 KB
  unsigned int* ctrl = (unsigned int*)(ws + off); off += 256;                   // cursor+done
  uint2* pairs = (uint2*)(ws + off);                                            // ~70 MB max

  prep_kernel<<<dim3(N + 1), dim3(256), 0, stream>>>(E, Ebf, norms, an_sq, (unsigned int*)accs, ctrl);
  gemm_min_kernel<<<dim3(NTRI), dim3(256), 0, stream>>>(Ebf, norms, targets, an_sq, pairs, ctrl);
  loss_kernel<<<dim3(LOSSB), dim3(256), 0, stream>>>(pairs, an_sq, accs, ctrl, out);
}